// Round 8
// baseline (2101.169 us; speedup 1.0000x reference)
//
#include <hip/hip_runtime.h>
#include <math.h>

typedef float v2f __attribute__((ext_vector_type(2)));

#define LN2_INV 1.4426950408889634f

__device__ __forceinline__ float fexp2(float x) {
#if __has_builtin(__builtin_amdgcn_exp2f)
    return __builtin_amdgcn_exp2f(x);
#else
    return exp2f(x);
#endif
}

__device__ __forceinline__ int rdlane_i(int v, int k) {
    return __builtin_amdgcn_readlane(v, k);
}

// Packed fp32 FMA: ACC = A * B + ACC on both 32-bit halves (one instruction).
#define PKFMA(ACC, A, B) \
    asm("v_pk_fma_f32 %0, %1, %2, %0" : "+v"(ACC) : "v"(A), "v"(B));

// v += dpp_shifted(v) within 16-lane rows; shifted-in lanes contribute 0.
#define DPP_ROW_ADD(V, CTRL) \
    V += __int_as_float(__builtin_amdgcn_update_dpp(0, __float_as_int(V), CTRL, 0xf, 0xf, true));

// ---------------------------------------------------------------------------
// k_h0: h0 = relu(x @ f_W + f_b), x [N,128], f_W [128,64]. 8 nodes/block.
// ---------------------------------------------------------------------------
__global__ __launch_bounds__(256) void k_h0(const float* __restrict__ x,
                                            const float* __restrict__ fW,
                                            const float* __restrict__ fb,
                                            float* __restrict__ h0) {
    __shared__ __align__(16) float xs[8 * 128];
    int t = threadIdx.x;
    int base = blockIdx.x * 8;
#pragma unroll
    for (int r = 0; r < 4; ++r) { int j = r * 256 + t; xs[j] = x[base * 128 + j]; }
    __syncthreads();
    int c = t & 63, half = t >> 6;
    float acc0 = fb[c], acc1 = fb[c];
    int m0 = half, m1 = half + 4;
#pragma unroll 8
    for (int k0 = 0; k0 < 128; k0 += 4) {
        float4 a = *(const float4*)&xs[m0 * 128 + k0];
        float4 b = *(const float4*)&xs[m1 * 128 + k0];
        float w0 = fW[(k0 + 0) * 64 + c], w1 = fW[(k0 + 1) * 64 + c];
        float w2 = fW[(k0 + 2) * 64 + c], w3 = fW[(k0 + 3) * 64 + c];
        acc0 = fmaf(a.x, w0, fmaf(a.y, w1, fmaf(a.z, w2, fmaf(a.w, w3, acc0))));
        acc1 = fmaf(b.x, w0, fmaf(b.y, w1, fmaf(b.z, w2, fmaf(b.w, w3, acc1))));
    }
    h0[(base + m0) * 64 + c] = fmaxf(acc0, 0.f);
    h0[(base + m1) * 64 + c] = fmaxf(acc1, 0.f);
}

// ---------------------------------------------------------------------------
// k_xlxr: xl = h@Wl + bl, xr = h@Wr + br, natural [N][256] layout (h*64+d).
// ---------------------------------------------------------------------------
__global__ __launch_bounds__(256) void k_xlxr(const float* __restrict__ h,
                                              const float* __restrict__ Wl,
                                              const float* __restrict__ Wr,
                                              const float* __restrict__ bl,
                                              const float* __restrict__ br,
                                              float* __restrict__ xl,
                                              float* __restrict__ xr) {
    __shared__ __align__(16) float hs[16 * 64];
    int t = threadIdx.x;
    int base = blockIdx.x * 16;
#pragma unroll
    for (int r = 0; r < 4; ++r) hs[r * 256 + t] = h[base * 64 + r * 256 + t];
    __syncthreads();
    float bL = bl[t], bR = br[t];
    float accl[16], accr[16];
#pragma unroll
    for (int m = 0; m < 16; ++m) { accl[m] = bL; accr[m] = bR; }
#pragma unroll 4
    for (int k0 = 0; k0 < 64; k0 += 4) {
        float wl[4], wr[4];
#pragma unroll
        for (int q = 0; q < 4; ++q) {
            wl[q] = Wl[(k0 + q) * 256 + t];
            wr[q] = Wr[(k0 + q) * 256 + t];
        }
#pragma unroll
        for (int m = 0; m < 16; ++m) {
            float4 hv = *(const float4*)&hs[m * 64 + k0];
            accl[m] = fmaf(hv.x, wl[0], fmaf(hv.y, wl[1], fmaf(hv.z, wl[2], fmaf(hv.w, wl[3], accl[m]))));
            accr[m] = fmaf(hv.x, wr[0], fmaf(hv.y, wr[1], fmaf(hv.z, wr[2], fmaf(hv.w, wr[3], accr[m]))));
        }
    }
#pragma unroll
    for (int m = 0; m < 16; ++m) {
        xl[(base + m) * 256 + t] = accl[m];
        xr[(base + m) * 256 + t] = accr[m];
    }
}

// ---------------------------------------------------------------------------
// k_wepk: repack We into k-pair layout for packed FMA:
//   Wepk[(kp*64+L)*8 + 2d+p] = We[(2kp+p)*256 + 4L+d],  kp<10, L<64, d<4, p<2
// ---------------------------------------------------------------------------
__global__ void k_wepk(const float* __restrict__ We, float* __restrict__ Wepk) {
    int t = blockIdx.x * 256 + threadIdx.x;     // 0..640*8-1 over (kp,L,d,p)
    if (t < 10 * 64 * 8) {
        int p = t & 1, d = (t >> 1) & 3, L = (t >> 3) & 63, kp = t >> 9;
        Wepk[t] = We[(2 * kp + p) * 256 + 4 * L + d];
    }
}

// ---------------------------------------------------------------------------
// CSR build. rec record (stride 24 ints): [0..19] = relu edge-MLP s_k,
// [20] = src node, [21..23] pad.
// ---------------------------------------------------------------------------
__global__ void k_zero(int* __restrict__ deg, int* __restrict__ counter, int Nn) {
    int i = blockIdx.x * 256 + threadIdx.x;
    if (i < Nn) deg[i] = 0;
    if (i == 0) *counter = 0;
}

__global__ void k_count(const int* __restrict__ dstArr, int* __restrict__ deg, int Ee) {
    int e = blockIdx.x * 256 + threadIdx.x;
    if (e < Ee) atomicAdd(&deg[dstArr[e]], 1);
}

__global__ void k_alloc(const int* __restrict__ deg, int* __restrict__ counter,
                        int* __restrict__ start, int* __restrict__ cursor, int Nn) {
    int n = blockIdx.x * 256 + threadIdx.x;
    if (n < Nn) {
        int d = deg[n];
        int b = atomicAdd(counter, d);
        start[n] = b;
        cursor[n] = b;
    }
}

__global__ void k_fill(const int* __restrict__ dstArr, const int* __restrict__ srcArr,
                       const float* __restrict__ eattr, const float* __restrict__ feW,
                       const float* __restrict__ feb, int* __restrict__ cursor,
                       int* __restrict__ rec, int Ee) {
    int e = blockIdx.x * 256 + threadIdx.x;
    if (e >= Ee) return;
    float a0 = eattr[2 * e], a1 = eattr[2 * e + 1];
    int p = atomicAdd(&cursor[dstArr[e]], 1);
    float* r = (float*)(rec + (size_t)p * 24);
    float s[20];
#pragma unroll
    for (int k = 0; k < 20; ++k)
        s[k] = fmaxf(fmaf(a0, feW[k], fmaf(a1, feW[20 + k], feb[k])), 0.f);
#pragma unroll
    for (int j = 0; j < 5; ++j)
        ((float4*)r)[j] = make_float4(s[4 * j], s[4 * j + 1], s[4 * j + 2], s[4 * j + 3]);
    ((int*)r)[20] = srcArr[e];
}

// ---------------------------------------------------------------------------
// Degree counting-sort (descending): bin = 255-min(deg,255); ascending bins.
// ---------------------------------------------------------------------------
__global__ void k_sort0(int* __restrict__ hist, int* __restrict__ hcur) {
    int t = threadIdx.x;
    hist[t] = 0;
    hcur[t] = 0;
}

__global__ void k_sort1(const int* __restrict__ deg, int* __restrict__ hist, int Nn) {
    int n = blockIdx.x * 256 + threadIdx.x;
    if (n < Nn) {
        int b = 255 - min(deg[n], 255);
        atomicAdd(&hist[b], 1);
    }
}

__global__ void k_sort2(const int* __restrict__ hist, int* __restrict__ hoff) {
    __shared__ int hs[256];
    int t = threadIdx.x;
    hs[t] = hist[t];
    __syncthreads();
    int s = 0;
    for (int j = 0; j < 256; ++j) if (j < t) s += hs[j];
    hoff[t] = s;
}

__global__ void k_sort3(const int* __restrict__ deg, const int* __restrict__ hoff,
                        int* __restrict__ hcur, int* __restrict__ order, int Nn) {
    int n = blockIdx.x * 256 + threadIdx.x;
    if (n < Nn) {
        int b = 255 - min(deg[n], 255);
        int pos = hoff[b] + atomicAdd(&hcur[b], 1);
        order[pos] = n;
    }
}

// ---------------------------------------------------------------------------
// k_edge: one wave per dst node (degree-sorted order), lane = h*16+g (natural
// h*64+d float4 order). Per edge: record dword/lane + readlane broadcast of
// k-pairs feeding v_pk_fma_f32 (2 MACs/inst), DPP row-reduce, 1 exp2.
// Records prefetched 2 ahead, xl gather 1 ahead (the proven R4 pipeline).
// ---------------------------------------------------------------------------
__global__ __launch_bounds__(256, 4) void k_edge(
    const float4* __restrict__ xl4p, const float4* __restrict__ xr4p,
    const float* __restrict__ att, const v2f* __restrict__ wepk,
    const int* __restrict__ rec, const int* __restrict__ start,
    const int* __restrict__ deg, const int* __restrict__ order,
    const float* __restrict__ bias, float* __restrict__ hout, int Nn) {
    const int lane = threadIdx.x & 63;
    const int wid = (int)((blockIdx.x * 256u + threadIdx.x) >> 6);
    if (wid >= Nn) return;
    const int n = order[wid];

    const int dn = __builtin_amdgcn_readfirstlane(deg[n]);
    float4 bias4 = ((const float4*)bias)[lane & 15];
    if (dn == 0) {
        if (lane < 16) {
            float4 o = make_float4(fmaxf(bias4.x, 0.f), fmaxf(bias4.y, 0.f),
                                   fmaxf(bias4.z, 0.f), fmaxf(bias4.w, 0.f));
            ((float4*)hout)[(size_t)n * 16 + lane] = o;
        }
        return;
    }
    const int s0 = __builtin_amdgcn_readfirstlane(start[n]);
    const int* rb = rec + (size_t)s0 * 24 + (lane & 31);

    float4 attv = ((const float4*)att)[lane];
    float4 aA = make_float4(0.6f * LN2_INV * attv.x, 0.6f * LN2_INV * attv.y,
                            0.6f * LN2_INV * attv.z, 0.6f * LN2_INV * attv.w);
    float4 aB = make_float4(0.4f * LN2_INV * attv.x, 0.4f * LN2_INV * attv.y,
                            0.4f * LN2_INV * attv.z, 0.4f * LN2_INV * attv.w);
    float4 xrv = xr4p[(size_t)n * 64 + lane];
    const int bperm = ((lane & 48) | 15) << 2;
    const v2f* wp = wepk + (size_t)lane * 4;    // [kp*256 + lane*4 + d]

    float acc0 = 0.f, acc1 = 0.f, acc2 = 0.f, acc3 = 0.f;
    float l = 0.f;

    // prologue: records for edges 0,1; xl gather for edge 0
    int i1 = dn > 1 ? 1 : 0;
    int rv0 = rb[0];
    int rv1 = rb[(size_t)i1 * 24];
    int src0 = rdlane_i(rv0, 20);
    float4 xl0 = xl4p[(size_t)src0 * 64 + lane];

    for (int i = 0; i < dn; ++i) {
        // prefetch: record i+2, xl gather i+1
        int i2 = (i + 2 < dn) ? (i + 2) : (dn - 1);
        int rv2 = rb[(size_t)i2 * 24];
        int src1 = rdlane_i(rv1, 20);
        float4 xl1 = xl4p[(size_t)src1 * 64 + lane];

        // ee via packed FMA over k-pairs: a_d += {s2k,s2k+1}*{We2k_d,We2k+1_d}
        v2f a0v = {0.f, 0.f}, a1v = {0.f, 0.f}, a2v = {0.f, 0.f}, a3v = {0.f, 0.f};
#pragma unroll
        for (int kp = 0; kp < 10; ++kp) {
            v2f skp;
            skp.x = __int_as_float(rdlane_i(rv0, 2 * kp));
            skp.y = __int_as_float(rdlane_i(rv0, 2 * kp + 1));
            v2f w0 = wp[kp * 256 + 0];
            v2f w1 = wp[kp * 256 + 1];
            v2f w2 = wp[kp * 256 + 2];
            v2f w3 = wp[kp * 256 + 3];
            PKFMA(a0v, skp, w0)
            PKFMA(a1v, skp, w1)
            PKFMA(a2v, skp, w2)
            PKFMA(a3v, skp, w3)
        }

        float v0 = (xl0.x + xrv.x) + (a0v.x + a0v.y);
        float v1 = (xl0.y + xrv.y) + (a1v.x + a1v.y);
        float v2 = (xl0.z + xrv.z) + (a2v.x + a2v.y);
        float v3 = (xl0.w + xrv.w) + (a3v.x + a3v.y);

        float tt = aB.x * __builtin_fabsf(v0);
        tt = fmaf(aA.x, v0, tt);
        tt = fmaf(aB.y, __builtin_fabsf(v1), tt);
        tt = fmaf(aA.y, v1, tt);
        tt = fmaf(aB.z, __builtin_fabsf(v2), tt);
        tt = fmaf(aA.z, v2, tt);
        tt = fmaf(aB.w, __builtin_fabsf(v3), tt);
        tt = fmaf(aA.w, v3, tt);
        DPP_ROW_ADD(tt, 0x111)
        DPP_ROW_ADD(tt, 0x112)
        DPP_ROW_ADD(tt, 0x114)
        DPP_ROW_ADD(tt, 0x118)
        float sc = __int_as_float(
            __builtin_amdgcn_ds_bpermute(bperm, __float_as_int(tt)));
        float w_ = fexp2(sc);
        l += w_;
        acc0 = fmaf(w_, xl0.x, acc0);
        acc1 = fmaf(w_, xl0.y, acc1);
        acc2 = fmaf(w_, xl0.z, acc2);
        acc3 = fmaf(w_, xl0.w, acc3);

        rv0 = rv1; rv1 = rv2; xl0 = xl1;
    }

    // epilogue: res = relu(bias + 0.25 * sum_h acc_h / l_h)
    float inv = 0.25f / l;
    float4 r = make_float4(acc0 * inv, acc1 * inv, acc2 * inv, acc3 * inv);
    r.x += __shfl_xor(r.x, 16, 64); r.x += __shfl_xor(r.x, 32, 64);
    r.y += __shfl_xor(r.y, 16, 64); r.y += __shfl_xor(r.y, 32, 64);
    r.z += __shfl_xor(r.z, 16, 64); r.z += __shfl_xor(r.z, 32, 64);
    r.w += __shfl_xor(r.w, 16, 64); r.w += __shfl_xor(r.w, 32, 64);
    if (lane < 16) {
        float4 o = make_float4(fmaxf(r.x + bias4.x, 0.f), fmaxf(r.y + bias4.y, 0.f),
                               fmaxf(r.z + bias4.z, 0.f), fmaxf(r.w + bias4.w, 0.f));
        ((float4*)hout)[(size_t)n * 16 + lane] = o;
    }
}

// ---------------------------------------------------------------------------
extern "C" void kernel_launch(void* const* d_in, const int* in_sizes, int n_in,
                              void* d_out, int out_size, void* d_ws, size_t ws_size,
                              hipStream_t stream) {
    const float* x     = (const float*)d_in[0];
    const float* eattr = (const float*)d_in[1];
    const int*   eidx  = (const int*)d_in[2];
    const float* fW    = (const float*)d_in[3];
    const float* fb    = (const float*)d_in[4];
    const float* feW   = (const float*)d_in[5];
    const float* feb   = (const float*)d_in[6];
    const float* Wl    = (const float*)d_in[7];
    const float* bl    = (const float*)d_in[8];
    const float* Wr    = (const float*)d_in[9];
    const float* br    = (const float*)d_in[10];
    const float* We    = (const float*)d_in[11];
    const float* att   = (const float*)d_in[12];
    const float* bias  = (const float*)d_in[13];
    float* out = (float*)d_out;

    const int N = in_sizes[0] / 128;   // 50000
    const int E = in_sizes[1] / 2;     // 800000
    const int* srcArr = eidx;
    const int* dstArr = eidx + E;

    char* p = (char*)d_ws;
    auto alloc = [&](size_t bytes) -> char* {
        char* r = p;
        p += (bytes + 255) & ~(size_t)255;
        return r;
    };
    float* hA   = (float*)alloc((size_t)N * 64 * 4);
    float* hB   = (float*)alloc((size_t)N * 64 * 4);
    float* xl   = (float*)alloc((size_t)N * 256 * 4);
    float* xr   = (float*)alloc((size_t)N * 256 * 4);
    float* Wepk = (float*)alloc(10 * 64 * 8 * 4);
    int* deg    = (int*)alloc((size_t)N * 4);
    int* start  = (int*)alloc((size_t)N * 4);
    int* cursor = (int*)alloc((size_t)N * 4);
    int* counter = (int*)alloc(256);
    int* hist   = (int*)alloc(256 * 4);
    int* hoff   = (int*)alloc(256 * 4);
    int* hcur   = (int*)alloc(256 * 4);
    int* order  = (int*)alloc((size_t)N * 4);
    int* rec    = (int*)alloc((size_t)E * 24 * 4 + 256);

    k_h0<<<N / 8, 256, 0, stream>>>(x, fW, fb, hA);
    k_wepk<<<20, 256, 0, stream>>>(We, Wepk);
    k_zero<<<(N + 255) / 256, 256, 0, stream>>>(deg, counter, N);
    k_count<<<(E + 255) / 256, 256, 0, stream>>>(dstArr, deg, E);
    k_alloc<<<(N + 255) / 256, 256, 0, stream>>>(deg, counter, start, cursor, N);
    k_fill<<<(E + 255) / 256, 256, 0, stream>>>(dstArr, srcArr, eattr, feW, feb,
                                                cursor, rec, E);
    k_sort0<<<1, 256, 0, stream>>>(hist, hcur);
    k_sort1<<<(N + 255) / 256, 256, 0, stream>>>(deg, hist, N);
    k_sort2<<<1, 256, 0, stream>>>(hist, hoff);
    k_sort3<<<(N + 255) / 256, 256, 0, stream>>>(deg, hoff, hcur, order, N);

    const float* hin = hA;
    for (int layer = 0; layer < 3; ++layer) {
        float* hout = (layer == 2) ? out : ((layer == 0) ? hB : hA);
        k_xlxr<<<N / 16, 256, 0, stream>>>(hin, Wl, Wr, bl, br, xl, xr);
        k_edge<<<(N * 64) / 256, 256, 0, stream>>>(
            (const float4*)xl, (const float4*)xr, att, (const v2f*)Wepk,
            rec, start, deg, order, bias, hout, N);
        hin = hout;
    }
}

// Round 9
// 2024.956 us; speedup vs baseline: 1.0376x; 1.0376x over previous
//
#include <hip/hip_runtime.h>
#include <math.h>

typedef float v2f __attribute__((ext_vector_type(2)));

#define LN2_INV 1.4426950408889634f

__device__ __forceinline__ float fexp2(float x) {
#if __has_builtin(__builtin_amdgcn_exp2f)
    return __builtin_amdgcn_exp2f(x);
#else
    return exp2f(x);
#endif
}

__device__ __forceinline__ int rdlane_i(int v, int k) {
    return __builtin_amdgcn_readlane(v, k);
}

// Packed fp32 FMA: ACC += SK * W. SK is an SGPR pair holding {s,s} (broadcast),
// W and ACC are aligned VGPR pairs. One VOP3P instruction = 2 MACs/lane.
#define PKFMA_S(ACC, SK, W) \
    asm("v_pk_fma_f32 %0, %1, %2, %0" : "+v"(ACC) : "s"(SK), "v"(W));
// Packed fp32 add: D = A + B.
#define PKADD(D, A, B) \
    asm("v_pk_add_f32 %0, %1, %2" : "=v"(D) : "v"(A), "v"(B));

// v += dpp_shifted(v) within 16-lane rows; shifted-in lanes contribute 0.
#define DPP_ROW_ADD(V, CTRL) \
    V += __int_as_float(__builtin_amdgcn_update_dpp(0, __float_as_int(V), CTRL, 0xf, 0xf, true));

// ---------------------------------------------------------------------------
// k_h0: h0 = relu(x @ f_W + f_b), x [N,128], f_W [128,64]. 8 nodes/block.
// ---------------------------------------------------------------------------
__global__ __launch_bounds__(256) void k_h0(const float* __restrict__ x,
                                            const float* __restrict__ fW,
                                            const float* __restrict__ fb,
                                            float* __restrict__ h0) {
    __shared__ __align__(16) float xs[8 * 128];
    int t = threadIdx.x;
    int base = blockIdx.x * 8;
#pragma unroll
    for (int r = 0; r < 4; ++r) { int j = r * 256 + t; xs[j] = x[base * 128 + j]; }
    __syncthreads();
    int c = t & 63, half = t >> 6;
    float acc0 = fb[c], acc1 = fb[c];
    int m0 = half, m1 = half + 4;
#pragma unroll 8
    for (int k0 = 0; k0 < 128; k0 += 4) {
        float4 a = *(const float4*)&xs[m0 * 128 + k0];
        float4 b = *(const float4*)&xs[m1 * 128 + k0];
        float w0 = fW[(k0 + 0) * 64 + c], w1 = fW[(k0 + 1) * 64 + c];
        float w2 = fW[(k0 + 2) * 64 + c], w3 = fW[(k0 + 3) * 64 + c];
        acc0 = fmaf(a.x, w0, fmaf(a.y, w1, fmaf(a.z, w2, fmaf(a.w, w3, acc0))));
        acc1 = fmaf(b.x, w0, fmaf(b.y, w1, fmaf(b.z, w2, fmaf(b.w, w3, acc1))));
    }
    h0[(base + m0) * 64 + c] = fmaxf(acc0, 0.f);
    h0[(base + m1) * 64 + c] = fmaxf(acc1, 0.f);
}

// ---------------------------------------------------------------------------
// k_xlxr: xl = h@Wl + bl, xr = h@Wr + br, natural [N][256] layout (h*64+d).
// ---------------------------------------------------------------------------
__global__ __launch_bounds__(256) void k_xlxr(const float* __restrict__ h,
                                              const float* __restrict__ Wl,
                                              const float* __restrict__ Wr,
                                              const float* __restrict__ bl,
                                              const float* __restrict__ br,
                                              float* __restrict__ xl,
                                              float* __restrict__ xr) {
    __shared__ __align__(16) float hs[16 * 64];
    int t = threadIdx.x;
    int base = blockIdx.x * 16;
#pragma unroll
    for (int r = 0; r < 4; ++r) hs[r * 256 + t] = h[base * 64 + r * 256 + t];
    __syncthreads();
    float bL = bl[t], bR = br[t];
    float accl[16], accr[16];
#pragma unroll
    for (int m = 0; m < 16; ++m) { accl[m] = bL; accr[m] = bR; }
#pragma unroll 4
    for (int k0 = 0; k0 < 64; k0 += 4) {
        float wl[4], wr[4];
#pragma unroll
        for (int q = 0; q < 4; ++q) {
            wl[q] = Wl[(k0 + q) * 256 + t];
            wr[q] = Wr[(k0 + q) * 256 + t];
        }
#pragma unroll
        for (int m = 0; m < 16; ++m) {
            float4 hv = *(const float4*)&hs[m * 64 + k0];
            accl[m] = fmaf(hv.x, wl[0], fmaf(hv.y, wl[1], fmaf(hv.z, wl[2], fmaf(hv.w, wl[3], accl[m]))));
            accr[m] = fmaf(hv.x, wr[0], fmaf(hv.y, wr[1], fmaf(hv.z, wr[2], fmaf(hv.w, wr[3], accr[m]))));
        }
    }
#pragma unroll
    for (int m = 0; m < 16; ++m) {
        xl[(base + m) * 256 + t] = accl[m];
        xr[(base + m) * 256 + t] = accr[m];
    }
}

// ---------------------------------------------------------------------------
// CSR build. rec record (stride 24 ints): [0..19] = relu edge-MLP s_k,
// [20] = src node, [21..23] pad.
// ---------------------------------------------------------------------------
__global__ void k_zero(int* __restrict__ deg, int* __restrict__ counter, int Nn) {
    int i = blockIdx.x * 256 + threadIdx.x;
    if (i < Nn) deg[i] = 0;
    if (i == 0) *counter = 0;
}

__global__ void k_count(const int* __restrict__ dstArr, int* __restrict__ deg, int Ee) {
    int e = blockIdx.x * 256 + threadIdx.x;
    if (e < Ee) atomicAdd(&deg[dstArr[e]], 1);
}

__global__ void k_alloc(const int* __restrict__ deg, int* __restrict__ counter,
                        int* __restrict__ start, int* __restrict__ cursor, int Nn) {
    int n = blockIdx.x * 256 + threadIdx.x;
    if (n < Nn) {
        int d = deg[n];
        int b = atomicAdd(counter, d);
        start[n] = b;
        cursor[n] = b;
    }
}

__global__ void k_fill(const int* __restrict__ dstArr, const int* __restrict__ srcArr,
                       const float* __restrict__ eattr, const float* __restrict__ feW,
                       const float* __restrict__ feb, int* __restrict__ cursor,
                       int* __restrict__ rec, int Ee) {
    int e = blockIdx.x * 256 + threadIdx.x;
    if (e >= Ee) return;
    float a0 = eattr[2 * e], a1 = eattr[2 * e + 1];
    int p = atomicAdd(&cursor[dstArr[e]], 1);
    float* r = (float*)(rec + (size_t)p * 24);
    float s[20];
#pragma unroll
    for (int k = 0; k < 20; ++k)
        s[k] = fmaxf(fmaf(a0, feW[k], fmaf(a1, feW[20 + k], feb[k])), 0.f);
#pragma unroll
    for (int j = 0; j < 5; ++j)
        ((float4*)r)[j] = make_float4(s[4 * j], s[4 * j + 1], s[4 * j + 2], s[4 * j + 3]);
    ((int*)r)[20] = srcArr[e];
}

// ---------------------------------------------------------------------------
// k_edge: one wave per dst node, lane = h*16+g (natural h*64+d float4 order).
// R4 pipeline (records 2 ahead, xl gather 1 ahead, We via immediate-offset
// dwordx4 reloads) with the ee inner product and v-sum in v_pk_fma_f32 /
// v_pk_add_f32 (2 MACs per instruction; broadcast scalar via SGPR pair).
// ---------------------------------------------------------------------------
__global__ __launch_bounds__(256, 3) void k_edge(
    const float4* __restrict__ xl4p, const float4* __restrict__ xr4p,
    const float* __restrict__ att, const float4* __restrict__ We4,
    const int* __restrict__ rec, const int* __restrict__ start,
    const int* __restrict__ deg, const float* __restrict__ bias,
    float* __restrict__ hout, int Nn) {
    const int lane = threadIdx.x & 63;
    const int n = (int)((blockIdx.x * 256u + threadIdx.x) >> 6);
    if (n >= Nn) return;

    const int dn = __builtin_amdgcn_readfirstlane(deg[n]);
    float4 bias4 = ((const float4*)bias)[lane & 15];
    if (dn == 0) {
        if (lane < 16) {
            float4 o = make_float4(fmaxf(bias4.x, 0.f), fmaxf(bias4.y, 0.f),
                                   fmaxf(bias4.z, 0.f), fmaxf(bias4.w, 0.f));
            ((float4*)hout)[(size_t)n * 16 + lane] = o;
        }
        return;
    }
    const int s0 = __builtin_amdgcn_readfirstlane(start[n]);
    const int* rb = rec + (size_t)s0 * 24 + (lane & 31);

    float4 attv = ((const float4*)att)[lane];
    float4 aA = make_float4(0.6f * LN2_INV * attv.x, 0.6f * LN2_INV * attv.y,
                            0.6f * LN2_INV * attv.z, 0.6f * LN2_INV * attv.w);
    float4 aB = make_float4(0.4f * LN2_INV * attv.x, 0.4f * LN2_INV * attv.y,
                            0.4f * LN2_INV * attv.z, 0.4f * LN2_INV * attv.w);
    float4 xrv = xr4p[(size_t)n * 64 + lane];
    v2f xr01 = {xrv.x, xrv.y}, xr23 = {xrv.z, xrv.w};
    const int bperm = ((lane & 48) | 15) << 2;

    float acc0 = 0.f, acc1 = 0.f, acc2 = 0.f, acc3 = 0.f;
    float l = 0.f;

    // prologue: records for edges 0,1; xl gather for edge 0
    int i1 = dn > 1 ? 1 : 0;
    int rv0 = rb[0];
    int rv1 = rb[(size_t)i1 * 24];
    int src0 = rdlane_i(rv0, 20);
    float4 xl0 = xl4p[(size_t)src0 * 64 + lane];

    for (int i = 0; i < dn; ++i) {
        // prefetch: record i+2, xl gather i+1
        int i2 = (i + 2 < dn) ? (i + 2) : (dn - 1);
        int rv2 = rb[(size_t)i2 * 24];
        int src1 = rdlane_i(rv1, 20);
        float4 xl1 = xl4p[(size_t)src1 * 64 + lane];

        // ee via packed FMA; two independent chains (k and k+10) for ILP
        v2f eA01 = {0.f, 0.f}, eA23 = {0.f, 0.f};
        v2f eB01 = {0.f, 0.f}, eB23 = {0.f, 0.f};
#pragma unroll
        for (int k = 0; k < 10; ++k) {
            float4 wa = We4[k * 64 + lane];
            float4 wb = We4[(k + 10) * 64 + lane];
            float ska = __int_as_float(rdlane_i(rv0, k));
            float skb = __int_as_float(rdlane_i(rv0, k + 10));
            v2f sa = {ska, ska};           // SGPR pair {s,s} (scalar-pipe movs)
            v2f sb = {skb, skb};
            v2f wa01 = {wa.x, wa.y}, wa23 = {wa.z, wa.w};
            v2f wb01 = {wb.x, wb.y}, wb23 = {wb.z, wb.w};
            PKFMA_S(eA01, sa, wa01)
            PKFMA_S(eA23, sa, wa23)
            PKFMA_S(eB01, sb, wb01)
            PKFMA_S(eB23, sb, wb23)
        }
        v2f ee01, ee23;
        PKADD(ee01, eA01, eB01)
        PKADD(ee23, eA23, eB23)

        // v = xl + xr + ee (packed adds)
        v2f xl01 = {xl0.x, xl0.y}, xl23 = {xl0.z, xl0.w};
        v2f t01, t23, v01, v23;
        PKADD(t01, xl01, xr01)
        PKADD(t23, xl23, xr23)
        PKADD(v01, t01, ee01)
        PKADD(v23, t23, ee23)

        // score: sum_h att_h * lrelu(v) with lrelu = 0.6v + 0.4|v|
        float tt = aB.x * __builtin_fabsf(v01.x);
        tt = fmaf(aA.x, v01.x, tt);
        tt = fmaf(aB.y, __builtin_fabsf(v01.y), tt);
        tt = fmaf(aA.y, v01.y, tt);
        tt = fmaf(aB.z, __builtin_fabsf(v23.x), tt);
        tt = fmaf(aA.z, v23.x, tt);
        tt = fmaf(aB.w, __builtin_fabsf(v23.y), tt);
        tt = fmaf(aA.w, v23.y, tt);
        DPP_ROW_ADD(tt, 0x111)
        DPP_ROW_ADD(tt, 0x112)
        DPP_ROW_ADD(tt, 0x114)
        DPP_ROW_ADD(tt, 0x118)
        float sc = __int_as_float(
            __builtin_amdgcn_ds_bpermute(bperm, __float_as_int(tt)));
        float w_ = fexp2(sc);
        l += w_;
        acc0 = fmaf(w_, xl0.x, acc0);
        acc1 = fmaf(w_, xl0.y, acc1);
        acc2 = fmaf(w_, xl0.z, acc2);
        acc3 = fmaf(w_, xl0.w, acc3);

        rv0 = rv1; rv1 = rv2; xl0 = xl1;
    }

    // epilogue: res = relu(bias + 0.25 * sum_h acc_h / l_h)
    float inv = 0.25f / l;
    float4 r = make_float4(acc0 * inv, acc1 * inv, acc2 * inv, acc3 * inv);
    r.x += __shfl_xor(r.x, 16, 64); r.x += __shfl_xor(r.x, 32, 64);
    r.y += __shfl_xor(r.y, 16, 64); r.y += __shfl_xor(r.y, 32, 64);
    r.z += __shfl_xor(r.z, 16, 64); r.z += __shfl_xor(r.z, 32, 64);
    r.w += __shfl_xor(r.w, 16, 64); r.w += __shfl_xor(r.w, 32, 64);
    if (lane < 16) {
        float4 o = make_float4(fmaxf(r.x + bias4.x, 0.f), fmaxf(r.y + bias4.y, 0.f),
                               fmaxf(r.z + bias4.z, 0.f), fmaxf(r.w + bias4.w, 0.f));
        ((float4*)hout)[(size_t)n * 16 + lane] = o;
    }
}

// ---------------------------------------------------------------------------
extern "C" void kernel_launch(void* const* d_in, const int* in_sizes, int n_in,
                              void* d_out, int out_size, void* d_ws, size_t ws_size,
                              hipStream_t stream) {
    const float* x     = (const float*)d_in[0];
    const float* eattr = (const float*)d_in[1];
    const int*   eidx  = (const int*)d_in[2];
    const float* fW    = (const float*)d_in[3];
    const float* fb    = (const float*)d_in[4];
    const float* feW   = (const float*)d_in[5];
    const float* feb   = (const float*)d_in[6];
    const float* Wl    = (const float*)d_in[7];
    const float* bl    = (const float*)d_in[8];
    const float* Wr    = (const float*)d_in[9];
    const float* br    = (const float*)d_in[10];
    const float* We    = (const float*)d_in[11];
    const float* att   = (const float*)d_in[12];
    const float* bias  = (const float*)d_in[13];
    float* out = (float*)d_out;

    const int N = in_sizes[0] / 128;   // 50000
    const int E = in_sizes[1] / 2;     // 800000
    const int* srcArr = eidx;
    const int* dstArr = eidx + E;

    char* p = (char*)d_ws;
    auto alloc = [&](size_t bytes) -> char* {
        char* r = p;
        p += (bytes + 255) & ~(size_t)255;
        return r;
    };
    float* hA   = (float*)alloc((size_t)N * 64 * 4);
    float* hB   = (float*)alloc((size_t)N * 64 * 4);
    float* xl   = (float*)alloc((size_t)N * 256 * 4);
    float* xr   = (float*)alloc((size_t)N * 256 * 4);
    int* deg    = (int*)alloc((size_t)N * 4);
    int* start  = (int*)alloc((size_t)N * 4);
    int* cursor = (int*)alloc((size_t)N * 4);
    int* counter = (int*)alloc(256);
    int* rec    = (int*)alloc((size_t)E * 24 * 4 + 256);

    k_h0<<<N / 8, 256, 0, stream>>>(x, fW, fb, hA);
    k_zero<<<(N + 255) / 256, 256, 0, stream>>>(deg, counter, N);
    k_count<<<(E + 255) / 256, 256, 0, stream>>>(dstArr, deg, E);
    k_alloc<<<(N + 255) / 256, 256, 0, stream>>>(deg, counter, start, cursor, N);
    k_fill<<<(E + 255) / 256, 256, 0, stream>>>(dstArr, srcArr, eattr, feW, feb,
                                                cursor, rec, E);

    const float* hin = hA;
    for (int layer = 0; layer < 3; ++layer) {
        float* hout = (layer == 2) ? out : ((layer == 0) ? hB : hA);
        k_xlxr<<<N / 16, 256, 0, stream>>>(hin, Wl, Wr, bl, br, xl, xr);
        k_edge<<<(N * 64) / 256, 256, 0, stream>>>(
            (const float4*)xl, (const float4*)xr, att, (const float4*)We,
            rec, start, deg, bias, hout, N);
        hin = hout;
    }
}